// Round 10
// baseline (260.947 us; speedup 1.0000x reference)
//
#include <hip/hip_runtime.h>
#include <hip/hip_bf16.h>
#include <cstdint>

typedef unsigned short u16;
typedef __bf16 bf16x8 __attribute__((ext_vector_type(8)));
typedef float floatx4 __attribute__((ext_vector_type(4)));

#define AS1 __attribute__((address_space(1)))
#define AS3 __attribute__((address_space(3)))

#define SCHED0  __builtin_amdgcn_sched_barrier(0)
#define BARRIER __builtin_amdgcn_s_barrier()

// round-to-nearest-even f32 -> bf16 bits
static __device__ __forceinline__ u16 f2bf(float f) {
    union { float f; unsigned int u; } v; v.f = f;
    unsigned int u = v.u;
    return (u16)((u + 0x7FFFu + ((u >> 16) & 1u)) >> 16);
}

// LDS byte offset of a __shared__ address (AS3 pointers are 32-bit)
static __device__ __forceinline__ unsigned lds_off(const u16* p) {
    return (unsigned)(unsigned long long)(const AS3 u16*)p;
}
// inline-asm ds_read_b128; "=&v" early-clobber; manual counted lgkmcnt +
// SCHED0 order the consumers (rule #18).
static __device__ __forceinline__ bf16x8 ds_read8(unsigned off) {
    bf16x8 r;
    asm volatile("ds_read_b128 %0, %1" : "=&v"(r) : "v"(off));
    return r;
}

template <int N> __device__ __forceinline__ void wvm() {
    if constexpr (N == 0) asm volatile("s_waitcnt vmcnt(0)" ::: "memory");
    else if constexpr (N == 3) asm volatile("s_waitcnt vmcnt(3)" ::: "memory");
    else if constexpr (N == 4) asm volatile("s_waitcnt vmcnt(4)" ::: "memory");
    else if constexpr (N == 6) asm volatile("s_waitcnt vmcnt(6)" ::: "memory");
    else if constexpr (N == 8) asm volatile("s_waitcnt vmcnt(8)" ::: "memory");
}
template <int N> __device__ __forceinline__ void wlg() {
    if constexpr (N == 0) asm volatile("s_waitcnt lgkmcnt(0)" ::: "memory");
    else if constexpr (N == 4) asm volatile("s_waitcnt lgkmcnt(4)" ::: "memory");
    else if constexpr (N == 8) asm volatile("s_waitcnt lgkmcnt(8)" ::: "memory");
}

// ---------------------------------------------------------------------------
// prep (verbatim, passed): [0,1024) w1-T, [1024,2048) w2-T,
// [2048,10240) LayerNorm rows. 128x32 transpose tiles, 256B out segments.
// ---------------------------------------------------------------------------
__device__ __forceinline__ void transpose_body(
    const float* __restrict__ in, u16* __restrict__ out,
    int R, int Ccols, int bx, int by, int tid, float (*tile)[33])
{
    const int r0 = by * 128, c0 = bx * 32;
#pragma unroll
    for (int p = 0; p < 4; ++p) {
        const int f = p * 256 + tid;
        const int r = f >> 3, c4 = (f & 7) * 4;
        const float4 v = *(const float4*)&in[(size_t)(r0 + r) * Ccols + c0 + c4];
        tile[r][c4 + 0] = v.x; tile[r][c4 + 1] = v.y;
        tile[r][c4 + 2] = v.z; tile[r][c4 + 3] = v.w;
    }
    __syncthreads();
    const int wv = tid >> 6, ln = tid & 63;
#pragma unroll
    for (int i = 0; i < 8; ++i) {
        const int c = i * 4 + wv;
        ushort2 o = { f2bf(tile[ln * 2][c]), f2bf(tile[ln * 2 + 1][c]) };
        *(ushort2*)&out[(size_t)(c0 + c) * R + r0 + ln * 2] = o;
    }
}

__global__ __launch_bounds__(256)
void prep(const float* __restrict__ w1, const float* __restrict__ w2,
          const float* __restrict__ act, const float* __restrict__ ln_scale,
          const float* __restrict__ ln_bias,
          u16* __restrict__ W1t, u16* __restrict__ W2t, u16* __restrict__ X)
{
    __shared__ float tile[128][33];
    const int id  = blockIdx.x;
    const int tid = threadIdx.x;

    if (id < 1024) {
        transpose_body(w1, W1t, 1024, 4096, id & 127, id >> 7, tid, tile);
        return;
    }
    if (id < 2048) {
        const int t = id - 1024;
        transpose_body(w2, W2t, 4096, 1024, t & 31, t >> 5, tid, tile);
        return;
    }
    const int row = id - 2048;
    const float4 v = ((const float4*)(act + (size_t)row * 1024))[tid];
    float s  = v.x + v.y + v.z + v.w;
    float ss = v.x * v.x + v.y * v.y + v.z * v.z + v.w * v.w;
#pragma unroll
    for (int off = 32; off > 0; off >>= 1) {
        s  += __shfl_xor(s, off, 64);
        ss += __shfl_xor(ss, off, 64);
    }
    float* red = &tile[0][0];
    const int wave = tid >> 6, lane = tid & 63;
    if (lane == 0) { red[wave] = s; red[4 + wave] = ss; }
    __syncthreads();
    s  = red[0] + red[1] + red[2] + red[3];
    ss = red[4] + red[5] + red[6] + red[7];
    const float mu  = s * (1.0f / 1024.0f);
    const float var = ss * (1.0f / 1024.0f) - mu * mu;
    const float rs  = rsqrtf(var + 1e-5f);
    const float4 sc = ((const float4*)ln_scale)[tid];
    const float4 bi = ((const float4*)ln_bias)[tid];
    ushort4 o;
    o.x = f2bf((v.x - mu) * rs * sc.x + bi.x);
    o.y = f2bf((v.y - mu) * rs * sc.y + bi.y);
    o.z = f2bf((v.z - mu) * rs * sc.z + bi.z);
    o.w = f2bf((v.w - mu) * rs * sc.w + bi.w);
    ((ushort4*)(X + (size_t)row * 1024))[tid] = o;
}

// ---------------------------------------------------------------------------
// R16 GEMM1: H = relu(X @ W1t^T + b1), bf16.  M=8192 N=4096 K=1024.
// BM=BN=256, BK=32, QUAD-buffered LDS ring (4 x (16KB A + 16KB B) = 128KB),
// staged 3 TILES AHEAD (~4-phase / ~5900cy slack; the R15 residual-stall
// suspect was the 1-2-phase vmcnt(0) drain under full-chip load).
// 8 waves (2M x 4N), wave tile 128x64, acc[8][4]. 2 phases/K-tile, 16 MFMA
// each (same phase count & MFMA/phase as R15 -> isolates the depth lever):
//   ph0(t): MFMA mi0-3 (a03(t), bres(t) read @ph1(t-1)); read a47(t)[4];
//           stage A(t+3)[2]; wlg<4>; 16 MFMA; counted wvm; BAR
//   ph1(t): MFMA mi4-7 (a47(t), bres(t));     read a03(t+1)+bres(t+1)[8];
//           stage B(t+3)[2]; wlg<8>; 16 MFMA; BAR
// lgkm ledger: enter ph0: Q=8 [a03(t),bres(t)]; ph0 +4 -> wlg<4> retires 8;
//   ph1 +8 -> wlg<8> retires a47(4). Tail (t=NT-1): ph1 wlg<0>.
// vmcnt ledger (4 issues/tile: A@ph0, B@ph1, for t+3; oldest-first):
//   at ph0(t)-end: Q=[A,B(t+1), A,B(t+2), A(t+3)] = 10 -> wvm<6> retires
//   A,B(t+1) (consumed by ph1(t)'s reads, 4-phase slack). Tails:
//   t+3>=NT: wvm<4>; t+2>=NT: wvm<0>; last tile: none. Never 0 mid-loop.
// Race: buf(t-1)'s last reads (a47(t-1)@ph0) retire at ph1(t-1)'s wlg<8>,
// barrier before ph0(t) staging into buf((t+3)&3)=buf((t-1)&3) -> safe.
// Swizzle (proven in gemm2 R11): store slot s^((row>>1)&3), read slot
// quad^((l16>>1)&3) -> worst 2-way (free, m136). Loop unrolled x2 so all
// fragment arrays are static-indexed (rule #20).
// ---------------------------------------------------------------------------
__global__ __launch_bounds__(512, 2)
void gemm1(const u16* __restrict__ A, const u16* __restrict__ Bt,
           const float* __restrict__ bias, u16* __restrict__ H)
{
    constexpr int K = 1024, N = 4096, NT = 32;
    constexpr int ABUF = 256 * 32;       // u16 per ring slot (16KB)
    __shared__ __align__(16) u16 Alds[4 * ABUF];
    __shared__ __align__(16) u16 Blds[4 * ABUF];

    const int tid  = threadIdx.x;
    const int wave = tid >> 6;
    const int lane = tid & 63;
    const int quad = lane >> 4;
    const int l16  = lane & 15;
    const int key4 = (l16 >> 1) & 3;
    const int wm   = wave >> 2;          // 0..1
    const int wn   = wave & 3;           // 0..3

    const int id = blockIdx.x;
    const int bm = id & 31;              // bm-fastest
    const int bn = id >> 5;              // 0..15

    const u16* Ag = A  + (size_t)bm * 256 * K;
    const u16* Bg = Bt + (size_t)bn * 256 * K;

    // one stage issue = 512 lanes x 16B = 8KB = 128 rows x 64B.
    auto stA = [&](int buf, int i, int kt) {
        const int row = i * 128 + wave * 16 + (lane >> 2);
        const int col = ((lane & 3) ^ ((row >> 1) & 3)) * 8;
        __builtin_amdgcn_global_load_lds(
            (AS1 void*)(Ag + (size_t)row * K + kt * 32 + col),
            (AS3 void*)(&Alds[buf * ABUF + i * 4096 + wave * 512]), 16, 0, 0);
    };
    auto stB = [&](int buf, int i, int kt) {
        const int row = i * 128 + wave * 16 + (lane >> 2);
        const int col = ((lane & 3) ^ ((row >> 1) & 3)) * 8;
        __builtin_amdgcn_global_load_lds(
            (AS1 void*)(Bg + (size_t)row * K + kt * 32 + col),
            (AS3 void*)(&Blds[buf * ABUF + i * 4096 + wave * 512]), 16, 0, 0);
    };

    const unsigned Ab = lds_off(&Alds[0]);
    const unsigned Bb = lds_off(&Blds[0]);
    unsigned aoff[8], boff[4];           // byte offsets within a ring slot
#pragma unroll
    for (int mi = 0; mi < 8; ++mi)
        aoff[mi] = ((wm * 128 + mi * 16 + l16) * 32 + (quad ^ key4) * 8) * 2;
#pragma unroll
    for (int ni = 0; ni < 4; ++ni)
        boff[ni] = ((wn * 64 + ni * 16 + l16) * 32 + (quad ^ key4) * 8) * 2;

    floatx4 acc[8][4];
#pragma unroll
    for (int i = 0; i < 8; ++i)
#pragma unroll
        for (int j = 0; j < 4; ++j)
            acc[i][j] = (floatx4){0.f, 0.f, 0.f, 0.f};

    // prologue: stage tiles 0,1,2 (order A0,B0,A1,B1,A2,B2); retire t0 only
    stA(0, 0, 0); stA(0, 1, 0);  stB(0, 0, 0); stB(0, 1, 0);
    stA(1, 0, 1); stA(1, 1, 1);  stB(1, 0, 1); stB(1, 1, 1);
    stA(2, 0, 2); stA(2, 1, 2);  stB(2, 0, 2); stB(2, 1, 2);
    wvm<8>();
    SCHED0; BARRIER; SCHED0;

    bf16x8 a03A[4], a03B[4], bresA[4], bresB[4], a47[4];
#pragma unroll
    for (int j = 0; j < 4; ++j) a03A[j] = ds_read8(Ab + aoff[j]);
#pragma unroll
    for (int n = 0; n < 4; ++n) bresA[n] = ds_read8(Bb + boff[n]);

    // one K-tile: PH(t, curA03, curBres, nxtA03, nxtBres)
#define PHASES(t, cA, cB, nA, nB)                                             \
    do {                                                                      \
        const unsigned abc = Ab + (unsigned)(((t) & 3) * 16384);              \
        const unsigned abn = Ab + (unsigned)((((t) + 1) & 3) * 16384);        \
        const unsigned bbn = Bb + (unsigned)((((t) + 1) & 3) * 16384);        \
        /* ---- ph0 ---- */                                                   \
        _Pragma("unroll")                                                     \
        for (int j = 0; j < 4; ++j) a47[j] = ds_read8(abc + aoff[4 + j]);     \
        if ((t) + 3 < NT) { stA(((t) + 3) & 3, 0, (t) + 3);                   \
                            stA(((t) + 3) & 3, 1, (t) + 3); }                 \
        wlg<4>();                                                             \
        SCHED0;                                                               \
        __builtin_amdgcn_s_setprio(1);                                        \
        _Pragma("unroll")                                                     \
        for (int j = 0; j < 4; ++j)                                           \
            _Pragma("unroll")                                                 \
            for (int n = 0; n < 4; ++n)                                       \
                acc[j][n] = __builtin_amdgcn_mfma_f32_16x16x32_bf16(          \
                    cB[n], cA[j], acc[j][n], 0, 0, 0);                        \
        __builtin_amdgcn_s_setprio(0);                                        \
        SCHED0;                                                               \
        if ((t) + 3 < NT)      wvm<6>();                                      \
        else if ((t) + 2 < NT) wvm<4>();                                      \
        else if ((t) + 1 < NT) wvm<0>();                                      \
        BARRIER; SCHED0;                                                      \
        /* ---- ph1 ---- */                                                   \
        if ((t) + 1 < NT) {                                                   \
            _Pragma("unroll")                                                 \
            for (int j = 0; j < 4; ++j) nA[j] = ds_read8(abn + aoff[j]);      \
            _Pragma("unroll")                                                 \
            for (int n = 0; n < 4; ++n) nB[n] = ds_read8(bbn + boff[n]);      \
        }                                                                     \
        if ((t) + 3 < NT) { stB(((t) + 3) & 3, 0, (t) + 3);                   \
                            stB(((t) + 3) & 3, 1, (t) + 3); }                 \
        if ((t) + 1 < NT) wlg<8>(); else wlg<0>();                            \
        SCHED0;                                                               \
        __builtin_amdgcn_s_setprio(1);                                        \
        _Pragma("unroll")                                                     \
        for (int j = 0; j < 4; ++j)                                           \
            _Pragma("unroll")                                                 \
            for (int n = 0; n < 4; ++n)                                       \
                acc[4 + j][n] = __builtin_amdgcn_mfma_f32_16x16x32_bf16(      \
                    cB[n], a47[j], acc[4 + j][n], 0, 0, 0);                   \
        __builtin_amdgcn_s_setprio(0);                                        \
        SCHED0; BARRIER; SCHED0;                                              \
    } while (0)

    for (int tp = 0; tp < NT; tp += 2) {
        PHASES(tp,     a03A, bresA, a03B, bresB);   // even tile
        PHASES(tp + 1, a03B, bresB, a03A, bresA);   // odd tile
    }
#undef PHASES

    // epilogue: bf16 + bias + relu
    const int mbase = bm * 256 + wm * 128;
    const int nbase = bn * 256 + wn * 64;
#pragma unroll
    for (int mi = 0; mi < 8; ++mi) {
        const int m = mbase + mi * 16 + l16;
#pragma unroll
        for (int ni = 0; ni < 4; ++ni) {
            const int n0 = nbase + ni * 16 + quad * 4;
            const float4 bv = *(const float4*)&bias[n0];
            float v0 = fmaxf(acc[mi][ni][0] + bv.x, 0.f);
            float v1 = fmaxf(acc[mi][ni][1] + bv.y, 0.f);
            float v2 = fmaxf(acc[mi][ni][2] + bv.z, 0.f);
            float v3 = fmaxf(acc[mi][ni][3] + bv.w, 0.f);
            ushort4 o = { f2bf(v0), f2bf(v1), f2bf(v2), f2bf(v3) };
            *(ushort4*)&H[(size_t)m * N + n0] = o;
        }
    }
}

// ---------------------------------------------------------------------------
// GEMM2 (verbatim R11/R15, passed): out = H @ W2t^T + b2, fp32. M=8192
// N=1024 K=4096. BM=256 BN=128 (grid 256 = 1/CU), 8 waves (4M x 2N), wave
// 64x64. Triple-buffered kh-split LDS; cross-tile frag read-ahead; staging
// 2 tiles ahead; uniform vmcnt(6)/lgkmcnt(8); one barrier per phase.
// ---------------------------------------------------------------------------
__global__ __launch_bounds__(512, 2)
void gemm2(const u16* __restrict__ A, const u16* __restrict__ Bt,
           const float* __restrict__ bias, float* __restrict__ Cout)
{
    constexpr int K = 4096, N = 1024;
    constexpr int ASZ = 2 * 256 * 32;    // u16 per buffer (32KB)
    constexpr int BSZ = 2 * 128 * 32;    // u16 per buffer (16KB)
    __shared__ __align__(16) u16 Alds[3 * ASZ];   // 96KB
    __shared__ __align__(16) u16 Blds[3 * BSZ];   // 48KB

    const int tid  = threadIdx.x;
    const int wave = tid >> 6;
    const int lane = tid & 63;
    const int quad = lane >> 4;
    const int l16  = lane & 15;
    const int key4 = (l16 >> 1) & 3;
    const int wm   = wave >> 1;          // 0..3
    const int wn   = wave & 1;           // 0..1

    const int id = blockIdx.x;
    const int bm = id & 31;
    const int bn = id >> 5;

    const u16* Ag = A  + (size_t)bm * 256 * K;
    const u16* Bg = Bt + (size_t)bn * 128 * K;

    auto stA = [&](int buf, int kh, int c, int k0) {
        const int row = c * 128 + wave * 16 + (lane >> 2);
        const int col = kh * 32 + ((lane & 3) ^ ((row >> 1) & 3)) * 8;
        __builtin_amdgcn_global_load_lds(
            (AS1 void*)(Ag + (size_t)row * K + k0 + col),
            (AS3 void*)(&Alds[buf * ASZ + kh * 8192 + c * 4096 + wave * 512]),
            16, 0, 0);
    };
    auto stB = [&](int buf, int kh, int k0) {
        const int row = wave * 16 + (lane >> 2);
        const int col = kh * 32 + ((lane & 3) ^ ((row >> 1) & 3)) * 8;
        __builtin_amdgcn_global_load_lds(
            (AS1 void*)(Bg + (size_t)row * K + k0 + col),
            (AS3 void*)(&Blds[buf * BSZ + kh * 4096 + wave * 512]), 16, 0, 0);
    };

    const unsigned Ab = lds_off(&Alds[0]);
    const unsigned Bb = lds_off(&Blds[0]);
    unsigned aoff[4], boff[4];
#pragma unroll
    for (int mi = 0; mi < 4; ++mi)
        aoff[mi] = ((wm * 64 + mi * 16 + l16) * 32 + (quad ^ key4) * 8) * 2;
#pragma unroll
    for (int ni = 0; ni < 4; ++ni)
        boff[ni] = ((wn * 64 + ni * 16 + l16) * 32 + (quad ^ key4) * 8) * 2;

    floatx4 acc[4][4];
#pragma unroll
    for (int i = 0; i < 4; ++i)
#pragma unroll
        for (int j = 0; j < 4; ++j)
            acc[i][j] = (floatx4){0.f, 0.f, 0.f, 0.f};

    constexpr int NT = K / 64;           // 64

    stA(0, 0, 0, 0);  stA(0, 0, 1, 0);  stB(0, 0, 0);
    stA(0, 1, 0, 0);  stA(0, 1, 1, 0);  stB(0, 1, 0);
    stA(1, 0, 0, 64); stA(1, 0, 1, 64); stB(1, 0, 64);
    stA(1, 1, 0, 64); stA(1, 1, 1, 64); stB(1, 1, 64);
    wvm<6>();
    SCHED0; BARRIER; SCHED0;

    bf16x8 fa[2][4], fb[2][4];
#pragma unroll
    for (int i = 0; i < 4; ++i) {
        fa[0][i] = ds_read8(Ab + aoff[i]);
        fb[0][i] = ds_read8(Bb + boff[i]);
    }

    int bs0 = 0, bs1 = 1, bs2 = 2;
    for (int t = 0; t < NT; ++t) {
        const int k2 = (t + 2) * 64;
        const bool st  = (t + 2 < NT);
        const bool rd1 = (t + 1 < NT);
        const unsigned a0 = Ab + (unsigned)(bs0 * ASZ * 2);
        const unsigned b0 = Bb + (unsigned)(bs0 * BSZ * 2);
        const unsigned a1 = Ab + (unsigned)(bs1 * ASZ * 2);
        const unsigned b1 = Bb + (unsigned)(bs1 * BSZ * 2);

        // phase kh=0
#pragma unroll
        for (int i = 0; i < 4; ++i) {
            fa[1][i] = ds_read8(a0 + 16384u + aoff[i]);
            fb[1][i] = ds_read8(b0 + 8192u  + boff[i]);
        }
        if (st) { stA(bs2, 0, 0, k2); stA(bs2, 0, 1, k2); stB(bs2, 0, k2); }
        wlg<8>();
        SCHED0;
        __builtin_amdgcn_s_setprio(1);
#pragma unroll
        for (int mi = 0; mi < 4; ++mi)
#pragma unroll
            for (int ni = 0; ni < 4; ++ni)
                acc[mi][ni] = __builtin_amdgcn_mfma_f32_16x16x32_bf16(
                    fb[0][ni], fa[0][mi], acc[mi][ni], 0, 0, 0);
        __builtin_amdgcn_s_setprio(0);
        SCHED0;
        if (st)       wvm<6>();
        else if (rd1) wvm<3>();
        BARRIER; SCHED0;

        // phase kh=1
        if (rd1) {
#pragma unroll
            for (int i = 0; i < 4; ++i) {
                fa[0][i] = ds_read8(a1 + aoff[i]);
                fb[0][i] = ds_read8(b1 + boff[i]);
            }
        }
        if (st) { stA(bs2, 1, 0, k2); stA(bs2, 1, 1, k2); stB(bs2, 1, k2); }
        if (rd1) wlg<8>(); else wlg<0>();
        SCHED0;
        __builtin_amdgcn_s_setprio(1);
#pragma unroll
        for (int mi = 0; mi < 4; ++mi)
#pragma unroll
            for (int ni = 0; ni < 4; ++ni)
                acc[mi][ni] = __builtin_amdgcn_mfma_f32_16x16x32_bf16(
                    fb[1][ni], fa[1][mi], acc[mi][ni], 0, 0, 0);
        __builtin_amdgcn_s_setprio(0);
        SCHED0;
        if (st)       wvm<6>();
        else if (rd1) wvm<0>();
        BARRIER; SCHED0;

        const int tmp = bs0; bs0 = bs1; bs1 = bs2; bs2 = tmp;
    }

    const int mbase = bm * 256 + wm * 64;
    const int nbase = bn * 128 + wn * 64;
#pragma unroll
    for (int mi = 0; mi < 4; ++mi) {
        const int m = mbase + mi * 16 + l16;
#pragma unroll
        for (int ni = 0; ni < 4; ++ni) {
            const int n0 = nbase + ni * 16 + quad * 4;
            const float4 bv = *(const float4*)&bias[n0];
            float4 o = { acc[mi][ni][0] + bv.x, acc[mi][ni][1] + bv.y,
                         acc[mi][ni][2] + bv.z, acc[mi][ni][3] + bv.w };
            *(float4*)&Cout[(size_t)m * N + n0] = o;
        }
    }
}

// ---------------------------------------------------------------------------
// inputs: 0 act(4,2048,1024) f32, 1 mask(unused), 2 ln_scale(1024),
//         3 ln_bias(1024), 4 w1(1024,4096), 5 b1(4096), 6 w2(4096,1024),
//         7 b2(1024). out: (4,2048,1024) f32.
// ws (bf16 bits): X[8192*1024] | W1t[4096*1024] | W2t[1024*4096] | H[8192*4096]
// ---------------------------------------------------------------------------
extern "C" void kernel_launch(void* const* d_in, const int* in_sizes, int n_in,
                              void* d_out, int out_size, void* d_ws, size_t ws_size,
                              hipStream_t stream)
{
    const float* act      = (const float*)d_in[0];
    const float* ln_scale = (const float*)d_in[2];
    const float* ln_bias  = (const float*)d_in[3];
    const float* w1       = (const float*)d_in[4];
    const float* b1       = (const float*)d_in[5];
    const float* w2       = (const float*)d_in[6];
    const float* b2       = (const float*)d_in[7];
    float* out = (float*)d_out;

    const int M = 8192, C = 1024, CI = 4096;

    u16* X   = (u16*)d_ws;                 // [M][C]
    u16* W1t = X   + (size_t)M * C;        // [CI][C]
    u16* W2t = W1t + (size_t)CI * C;       // [C][CI]
    u16* H   = W2t + (size_t)C * CI;       // [M][CI]

    prep<<<10240, 256, 0, stream>>>(w1, w2, act, ln_scale, ln_bias, W1t, W2t, X);
    // H = relu(X @ W1 + b1): 512 blocks, BK=32 quad-ring, 3-tile-deep staging
    gemm1<<<(M / 256) * (CI / 256), 512, 0, stream>>>(X, W1t, b1, H);
    // out = H @ W2 + b2: 256 blocks = 1/CU, cross-tile read-ahead (R11)
    gemm2<<<(M / 256) * (C / 128), 512, 0, stream>>>(H, W2t, b2, out);
}

// Round 11
// 257.673 us; speedup vs baseline: 1.0127x; 1.0127x over previous
//
#include <hip/hip_runtime.h>
#include <hip/hip_bf16.h>
#include <cstdint>

typedef unsigned short u16;
typedef __bf16 bf16x8 __attribute__((ext_vector_type(8)));
typedef float floatx4 __attribute__((ext_vector_type(4)));

#define AS1 __attribute__((address_space(1)))
#define AS3 __attribute__((address_space(3)))

#define SCHED0  __builtin_amdgcn_sched_barrier(0)
#define BARRIER __builtin_amdgcn_s_barrier()

// round-to-nearest-even f32 -> bf16 bits
static __device__ __forceinline__ u16 f2bf(float f) {
    union { float f; unsigned int u; } v; v.f = f;
    unsigned int u = v.u;
    return (u16)((u + 0x7FFFu + ((u >> 16) & 1u)) >> 16);
}

// LDS byte offset of a __shared__ address (AS3 pointers are 32-bit)
static __device__ __forceinline__ unsigned lds_off(const u16* p) {
    return (unsigned)(unsigned long long)(const AS3 u16*)p;
}
// inline-asm ds_read_b128; "=&v" early-clobber; manual lgkmcnt + SCHED0
// order the consumers (rule #18).
static __device__ __forceinline__ bf16x8 ds_read8(unsigned off) {
    bf16x8 r;
    asm volatile("ds_read_b128 %0, %1" : "=&v"(r) : "v"(off));
    return r;
}

template <int N> __device__ __forceinline__ void wvm() {
    if constexpr (N == 0) asm volatile("s_waitcnt vmcnt(0)" ::: "memory");
    else if constexpr (N == 3) asm volatile("s_waitcnt vmcnt(3)" ::: "memory");
    else if constexpr (N == 4) asm volatile("s_waitcnt vmcnt(4)" ::: "memory");
    else if constexpr (N == 6) asm volatile("s_waitcnt vmcnt(6)" ::: "memory");
}
template <int N> __device__ __forceinline__ void wlg() {
    if constexpr (N == 0) asm volatile("s_waitcnt lgkmcnt(0)" ::: "memory");
    else if constexpr (N == 8) asm volatile("s_waitcnt lgkmcnt(8)" ::: "memory");
}

// ---------------------------------------------------------------------------
// prep (verbatim, passed): [0,1024) w1-T, [1024,2048) w2-T,
// [2048,10240) LayerNorm rows. 128x32 transpose tiles, 256B out segments.
// ---------------------------------------------------------------------------
__device__ __forceinline__ void transpose_body(
    const float* __restrict__ in, u16* __restrict__ out,
    int R, int Ccols, int bx, int by, int tid, float (*tile)[33])
{
    const int r0 = by * 128, c0 = bx * 32;
#pragma unroll
    for (int p = 0; p < 4; ++p) {
        const int f = p * 256 + tid;
        const int r = f >> 3, c4 = (f & 7) * 4;
        const float4 v = *(const float4*)&in[(size_t)(r0 + r) * Ccols + c0 + c4];
        tile[r][c4 + 0] = v.x; tile[r][c4 + 1] = v.y;
        tile[r][c4 + 2] = v.z; tile[r][c4 + 3] = v.w;
    }
    __syncthreads();
    const int wv = tid >> 6, ln = tid & 63;
#pragma unroll
    for (int i = 0; i < 8; ++i) {
        const int c = i * 4 + wv;
        ushort2 o = { f2bf(tile[ln * 2][c]), f2bf(tile[ln * 2 + 1][c]) };
        *(ushort2*)&out[(size_t)(c0 + c) * R + r0 + ln * 2] = o;
    }
}

__global__ __launch_bounds__(256)
void prep(const float* __restrict__ w1, const float* __restrict__ w2,
          const float* __restrict__ act, const float* __restrict__ ln_scale,
          const float* __restrict__ ln_bias,
          u16* __restrict__ W1t, u16* __restrict__ W2t, u16* __restrict__ X)
{
    __shared__ float tile[128][33];
    const int id  = blockIdx.x;
    const int tid = threadIdx.x;

    if (id < 1024) {
        transpose_body(w1, W1t, 1024, 4096, id & 127, id >> 7, tid, tile);
        return;
    }
    if (id < 2048) {
        const int t = id - 1024;
        transpose_body(w2, W2t, 4096, 1024, t & 31, t >> 5, tid, tile);
        return;
    }
    const int row = id - 2048;
    const float4 v = ((const float4*)(act + (size_t)row * 1024))[tid];
    float s  = v.x + v.y + v.z + v.w;
    float ss = v.x * v.x + v.y * v.y + v.z * v.z + v.w * v.w;
#pragma unroll
    for (int off = 32; off > 0; off >>= 1) {
        s  += __shfl_xor(s, off, 64);
        ss += __shfl_xor(ss, off, 64);
    }
    float* red = &tile[0][0];
    const int wave = tid >> 6, lane = tid & 63;
    if (lane == 0) { red[wave] = s; red[4 + wave] = ss; }
    __syncthreads();
    s  = red[0] + red[1] + red[2] + red[3];
    ss = red[4] + red[5] + red[6] + red[7];
    const float mu  = s * (1.0f / 1024.0f);
    const float var = ss * (1.0f / 1024.0f) - mu * mu;
    const float rs  = rsqrtf(var + 1e-5f);
    const float4 sc = ((const float4*)ln_scale)[tid];
    const float4 bi = ((const float4*)ln_bias)[tid];
    ushort4 o;
    o.x = f2bf((v.x - mu) * rs * sc.x + bi.x);
    o.y = f2bf((v.y - mu) * rs * sc.y + bi.y);
    o.z = f2bf((v.z - mu) * rs * sc.z + bi.z);
    o.w = f2bf((v.w - mu) * rs * sc.w + bi.w);
    ((ushort4*)(X + (size_t)row * 1024))[tid] = o;
}

// ---------------------------------------------------------------------------
// R17 GEMM1: H = relu(X @ W1t^T + b1), bf16.  M=8192 N=4096 K=1024.
// EXACT m201 phase discipline: per phase {in-phase ds_reads; stage; BAR1;
// lgkmcnt(0); setprio(1); 16 MFMA; setprio(0); [p3: counted wvm]; BAR2}.
// Reads issued BEFORE BAR1 hide under barrier arrival skew; lgkm0 after
// BAR1 is near-satisfied; NO mid-loop vmcnt(0) (the R11/R15 X ~450cy/phase).
//
// BM=BN=256, BK=64, 8 waves (2M x 4N), wave 128x64, acc[8][4] (AGPR).
// Buffers: A DOUBLE (2x32KB), staged 1 tile ahead @p0; B TRIPLE (3x32KB),
// staged 2 tiles ahead @p1. LDS = 160KB exactly (AITER attn runs 160KB on
// this chip, m243). Phase p: (mi-half = p&1, kh = p>>1); reads: p0: A03kh0
// + Bkh0 (8), p1: A47kh0 (4), p2: A03kh1 + Bkh1 (8), p3: A47kh1 (4).
//
// vmcnt ledger (all-DMA queue, sim-verified): prologue stages A0,B0,B1 ->
// wvm<4> retires A0,B0 (leaves B1). Steady: p0(t) +A(t+1), p1(t) +B(t+2);
// at p3(t)-end Q=12 -> wvm<4> retires A(t+1) [3-phase slack] + B(t+1)
// [6-phase slack], leaves B(t+2). Tails: t+2>=NT -> wvm<0> once (t=NT-2);
// last tile no wait. Stage conds: A iff t+1<NT, B iff t+2<NT.
// Races: stA(t+1)->buf (t+1)&1: its prior reads (p3(t-1)) complete at
// wlg0(p3(t-1)), >=1 barrier before p0(t). stB(t+2)->buf (t+2)%3 =
// (t-1)%3: last reads p2(t-1), >=2 barriers. All barriers uniform.
// Swizzle (0-conflict, R2..R16): store slot s^(row&7), read slot
// (kh*4+quad)^(l16&7).
// ---------------------------------------------------------------------------
__global__ __launch_bounds__(512, 2)
void gemm1(const u16* __restrict__ A, const u16* __restrict__ Bt,
           const float* __restrict__ bias, u16* __restrict__ H)
{
    constexpr int K = 1024, N = 4096, NT = 16;
    constexpr int ASZ = 256 * 64;        // u16 per buffer (32KB)
    __shared__ __align__(16) u16 Alds[2 * ASZ];   // 64KB
    __shared__ __align__(16) u16 Blds[3 * ASZ];   // 96KB

    const int tid  = threadIdx.x;
    const int wave = tid >> 6;
    const int lane = tid & 63;
    const int srow = lane >> 3;
    const int sst  = lane & 7;
    const int quad = lane >> 4;
    const int l16  = lane & 15;
    const int rkey = l16 & 7;
    const int wm   = wave >> 2;          // 0..1
    const int wn   = wave & 3;           // 0..3

    const int id = blockIdx.x;
    const int bm = id & 31;              // bm-fastest
    const int bn = id >> 5;              // 0..15

    const u16* Ag = A  + (size_t)bm * 256 * K;
    const u16* Bg = Bt + (size_t)bn * 256 * K;

    auto stA = [&](int buf, int c, int k0) {
        const int row = c * 64 + wave * 8 + srow;
        const int col = (sst ^ (row & 7)) * 8;
        __builtin_amdgcn_global_load_lds(
            (AS1 void*)(Ag + (size_t)row * K + k0 + col),
            (AS3 void*)(&Alds[buf * ASZ + c * 4096 + wave * 512]), 16, 0, 0);
    };
    auto stB = [&](int buf, int c, int k0) {
        const int row = c * 64 + wave * 8 + srow;
        const int col = (sst ^ (row & 7)) * 8;
        __builtin_amdgcn_global_load_lds(
            (AS1 void*)(Bg + (size_t)row * K + k0 + col),
            (AS3 void*)(&Blds[buf * ASZ + c * 4096 + wave * 512]), 16, 0, 0);
    };

    const unsigned Abase = lds_off(&Alds[0]);
    const unsigned Bbase = lds_off(&Blds[0]);
    unsigned aoff[8][2], boff[4][2];     // byte offsets within a buffer
#pragma unroll
    for (int mi = 0; mi < 8; ++mi)
#pragma unroll
        for (int kh = 0; kh < 2; ++kh)
            aoff[mi][kh] = ((wm * 128 + mi * 16 + l16) * 64 +
                            ((kh * 4 + quad) ^ rkey) * 8) * 2;
#pragma unroll
    for (int ni = 0; ni < 4; ++ni)
#pragma unroll
        for (int kh = 0; kh < 2; ++kh)
            boff[ni][kh] = ((wn * 64 + ni * 16 + l16) * 64 +
                            ((kh * 4 + quad) ^ rkey) * 8) * 2;

    floatx4 acc[8][4];
#pragma unroll
    for (int i = 0; i < 8; ++i)
#pragma unroll
        for (int j = 0; j < 4; ++j)
            acc[i][j] = (floatx4){0.f, 0.f, 0.f, 0.f};

    // prologue: A0 -> Abuf0; B0 -> Bbuf0; B1 -> Bbuf1. Retire A0,B0.
    stA(0, 0, 0); stA(0, 2, 0); stA(0, 1, 0); stA(0, 3, 0);
    stB(0, 0, 0); stB(0, 1, 0); stB(0, 2, 0); stB(0, 3, 0);
    stB(1, 0, 64); stB(1, 1, 64); stB(1, 2, 64); stB(1, 3, 64);
    wvm<4>();
    SCHED0; BARRIER; SCHED0;

    bf16x8 afr[4], bfr[4];
    int b0 = 0, b1 = 1, b2 = 2;          // B buffers of t, t+1, t+2
    for (int t = 0; t < NT; ++t) {
        const unsigned abc = Abase + (unsigned)((t & 1) * ASZ * 2);
        const unsigned bbc = Bbase + (unsigned)(b0 * ASZ * 2);
        const int nbA = (t + 1) & 1;
        const int k1 = (t + 1) * 64;
        const int k2 = (t + 2) * 64;

        // ---- p0: reads A03kh0 + Bkh0; stage A(t+1); MFMA acc[0-3] kh0 ----
#pragma unroll
        for (int j = 0; j < 4; ++j) afr[j] = ds_read8(abc + aoff[j][0]);
#pragma unroll
        for (int n = 0; n < 4; ++n) bfr[n] = ds_read8(bbc + boff[n][0]);
        if (t + 1 < NT) { stA(nbA, 0, k1); stA(nbA, 2, k1);
                          stA(nbA, 1, k1); stA(nbA, 3, k1); }
        SCHED0; BARRIER;
        wlg<0>();
        SCHED0;
        __builtin_amdgcn_s_setprio(1);
#pragma unroll
        for (int j = 0; j < 4; ++j)
#pragma unroll
            for (int n = 0; n < 4; ++n)
                acc[j][n] = __builtin_amdgcn_mfma_f32_16x16x32_bf16(
                    bfr[n], afr[j], acc[j][n], 0, 0, 0);
        __builtin_amdgcn_s_setprio(0);
        SCHED0; BARRIER; SCHED0;

        // ---- p1: reads A47kh0; stage B(t+2); MFMA acc[4-7] kh0 -----------
#pragma unroll
        for (int j = 0; j < 4; ++j) afr[j] = ds_read8(abc + aoff[4 + j][0]);
        if (t + 2 < NT) { stB(b2, 0, k2); stB(b2, 1, k2);
                          stB(b2, 2, k2); stB(b2, 3, k2); }
        SCHED0; BARRIER;
        wlg<0>();
        SCHED0;
        __builtin_amdgcn_s_setprio(1);
#pragma unroll
        for (int j = 0; j < 4; ++j)
#pragma unroll
            for (int n = 0; n < 4; ++n)
                acc[4 + j][n] = __builtin_amdgcn_mfma_f32_16x16x32_bf16(
                    bfr[n], afr[j], acc[4 + j][n], 0, 0, 0);
        __builtin_amdgcn_s_setprio(0);
        SCHED0; BARRIER; SCHED0;

        // ---- p2: reads A03kh1 + Bkh1; MFMA acc[0-3] kh1 ------------------
#pragma unroll
        for (int j = 0; j < 4; ++j) afr[j] = ds_read8(abc + aoff[j][1]);
#pragma unroll
        for (int n = 0; n < 4; ++n) bfr[n] = ds_read8(bbc + boff[n][1]);
        SCHED0; BARRIER;
        wlg<0>();
        SCHED0;
        __builtin_amdgcn_s_setprio(1);
#pragma unroll
        for (int j = 0; j < 4; ++j)
#pragma unroll
            for (int n = 0; n < 4; ++n)
                acc[j][n] = __builtin_amdgcn_mfma_f32_16x16x32_bf16(
                    bfr[n], afr[j], acc[j][n], 0, 0, 0);
        __builtin_amdgcn_s_setprio(0);
        SCHED0; BARRIER; SCHED0;

        // ---- p3: reads A47kh1; MFMA acc[4-7] kh1; counted wvm ------------
#pragma unroll
        for (int j = 0; j < 4; ++j) afr[j] = ds_read8(abc + aoff[4 + j][1]);
        SCHED0; BARRIER;
        wlg<0>();
        SCHED0;
        __builtin_amdgcn_s_setprio(1);
#pragma unroll
        for (int j = 0; j < 4; ++j)
#pragma unroll
            for (int n = 0; n < 4; ++n)
                acc[4 + j][n] = __builtin_amdgcn_mfma_f32_16x16x32_bf16(
                    bfr[n], afr[j], acc[4 + j][n], 0, 0, 0);
        __builtin_amdgcn_s_setprio(0);
        SCHED0;
        if (t + 2 < NT)      wvm<4>();   // retires A(t+1) [3ph], B(t+1) [6ph]
        else if (t + 1 < NT) wvm<0>();   // once, at t = NT-2
        BARRIER; SCHED0;

        const int tmp = b0; b0 = b1; b1 = b2; b2 = tmp;
    }

    // epilogue: bf16 + bias + relu
    const int mbase = bm * 256 + wm * 128;
    const int nbase = bn * 256 + wn * 64;
#pragma unroll
    for (int mi = 0; mi < 8; ++mi) {
        const int m = mbase + mi * 16 + l16;
#pragma unroll
        for (int ni = 0; ni < 4; ++ni) {
            const int n0 = nbase + ni * 16 + quad * 4;
            const float4 bv = *(const float4*)&bias[n0];
            float v0 = fmaxf(acc[mi][ni][0] + bv.x, 0.f);
            float v1 = fmaxf(acc[mi][ni][1] + bv.y, 0.f);
            float v2 = fmaxf(acc[mi][ni][2] + bv.z, 0.f);
            float v3 = fmaxf(acc[mi][ni][3] + bv.w, 0.f);
            ushort4 o = { f2bf(v0), f2bf(v1), f2bf(v2), f2bf(v3) };
            *(ushort4*)&H[(size_t)m * N + n0] = o;
        }
    }
}

// ---------------------------------------------------------------------------
// GEMM2 (verbatim R11/R15, passed): out = H @ W2t^T + b2, fp32. M=8192
// N=1024 K=4096. BM=256 BN=128 (grid 256 = 1/CU), 8 waves (4M x 2N), wave
// 64x64. Triple-buffered kh-split LDS; cross-tile frag read-ahead; staging
// 2 tiles ahead; uniform vmcnt(6)/lgkmcnt(8); one barrier per phase.
// ---------------------------------------------------------------------------
__global__ __launch_bounds__(512, 2)
void gemm2(const u16* __restrict__ A, const u16* __restrict__ Bt,
           const float* __restrict__ bias, float* __restrict__ Cout)
{
    constexpr int K = 4096, N = 1024;
    constexpr int ASZ = 2 * 256 * 32;    // u16 per buffer (32KB)
    constexpr int BSZ = 2 * 128 * 32;    // u16 per buffer (16KB)
    __shared__ __align__(16) u16 Alds[3 * ASZ];   // 96KB
    __shared__ __align__(16) u16 Blds[3 * BSZ];   // 48KB

    const int tid  = threadIdx.x;
    const int wave = tid >> 6;
    const int lane = tid & 63;
    const int quad = lane >> 4;
    const int l16  = lane & 15;
    const int key4 = (l16 >> 1) & 3;
    const int wm   = wave >> 1;          // 0..3
    const int wn   = wave & 1;           // 0..1

    const int id = blockIdx.x;
    const int bm = id & 31;
    const int bn = id >> 5;

    const u16* Ag = A  + (size_t)bm * 256 * K;
    const u16* Bg = Bt + (size_t)bn * 128 * K;

    auto stA = [&](int buf, int kh, int c, int k0) {
        const int row = c * 128 + wave * 16 + (lane >> 2);
        const int col = kh * 32 + ((lane & 3) ^ ((row >> 1) & 3)) * 8;
        __builtin_amdgcn_global_load_lds(
            (AS1 void*)(Ag + (size_t)row * K + k0 + col),
            (AS3 void*)(&Alds[buf * ASZ + kh * 8192 + c * 4096 + wave * 512]),
            16, 0, 0);
    };
    auto stB = [&](int buf, int kh, int k0) {
        const int row = wave * 16 + (lane >> 2);
        const int col = kh * 32 + ((lane & 3) ^ ((row >> 1) & 3)) * 8;
        __builtin_amdgcn_global_load_lds(
            (AS1 void*)(Bg + (size_t)row * K + k0 + col),
            (AS3 void*)(&Blds[buf * BSZ + kh * 4096 + wave * 512]), 16, 0, 0);
    };

    const unsigned Ab = lds_off(&Alds[0]);
    const unsigned Bb = lds_off(&Blds[0]);
    unsigned aoff[4], boff[4];
#pragma unroll
    for (int mi = 0; mi < 4; ++mi)
        aoff[mi] = ((wm * 64 + mi * 16 + l16) * 32 + (quad ^ key4) * 8) * 2;
#pragma unroll
    for (int ni = 0; ni < 4; ++ni)
        boff[ni] = ((wn * 64 + ni * 16 + l16) * 32 + (quad ^ key4) * 8) * 2;

    floatx4 acc[4][4];
#pragma unroll
    for (int i = 0; i < 4; ++i)
#pragma unroll
        for (int j = 0; j < 4; ++j)
            acc[i][j] = (floatx4){0.f, 0.f, 0.f, 0.f};

    constexpr int NT = K / 64;           // 64

    stA(0, 0, 0, 0);  stA(0, 0, 1, 0);  stB(0, 0, 0);
    stA(0, 1, 0, 0);  stA(0, 1, 1, 0);  stB(0, 1, 0);
    stA(1, 0, 0, 64); stA(1, 0, 1, 64); stB(1, 0, 64);
    stA(1, 1, 0, 64); stA(1, 1, 1, 64); stB(1, 1, 64);
    wvm<6>();
    SCHED0; BARRIER; SCHED0;

    bf16x8 fa[2][4], fb[2][4];
#pragma unroll
    for (int i = 0; i < 4; ++i) {
        fa[0][i] = ds_read8(Ab + aoff[i]);
        fb[0][i] = ds_read8(Bb + boff[i]);
    }

    int bs0 = 0, bs1 = 1, bs2 = 2;
    for (int t = 0; t < NT; ++t) {
        const int k2 = (t + 2) * 64;
        const bool st  = (t + 2 < NT);
        const bool rd1 = (t + 1 < NT);
        const unsigned a0 = Ab + (unsigned)(bs0 * ASZ * 2);
        const unsigned b0 = Bb + (unsigned)(bs0 * BSZ * 2);
        const unsigned a1 = Ab + (unsigned)(bs1 * ASZ * 2);
        const unsigned b1 = Bb + (unsigned)(bs1 * BSZ * 2);

        // phase kh=0
#pragma unroll
        for (int i = 0; i < 4; ++i) {
            fa[1][i] = ds_read8(a0 + 16384u + aoff[i]);
            fb[1][i] = ds_read8(b0 + 8192u  + boff[i]);
        }
        if (st) { stA(bs2, 0, 0, k2); stA(bs2, 0, 1, k2); stB(bs2, 0, k2); }
        wlg<8>();
        SCHED0;
        __builtin_amdgcn_s_setprio(1);
#pragma unroll
        for (int mi = 0; mi < 4; ++mi)
#pragma unroll
            for (int ni = 0; ni < 4; ++ni)
                acc[mi][ni] = __builtin_amdgcn_mfma_f32_16x16x32_bf16(
                    fb[0][ni], fa[0][mi], acc[mi][ni], 0, 0, 0);
        __builtin_amdgcn_s_setprio(0);
        SCHED0;
        if (st)       wvm<6>();
        else if (rd1) wvm<3>();
        BARRIER; SCHED0;

        // phase kh=1
        if (rd1) {
#pragma unroll
            for (int i = 0; i < 4; ++i) {
                fa[0][i] = ds_read8(a1 + aoff[i]);
                fb[0][i] = ds_read8(b1 + boff[i]);
            }
        }
        if (st) { stA(bs2, 1, 0, k2); stA(bs2, 1, 1, k2); stB(bs2, 1, k2); }
        if (rd1) wlg<8>(); else wlg<0>();
        SCHED0;
        __builtin_amdgcn_s_setprio(1);
#pragma unroll
        for (int mi = 0; mi < 4; ++mi)
#pragma unroll
            for (int ni = 0; ni < 4; ++ni)
                acc[mi][ni] = __builtin_amdgcn_mfma_f32_16x16x32_bf16(
                    fb[1][ni], fa[1][mi], acc[mi][ni], 0, 0, 0);
        __builtin_amdgcn_s_setprio(0);
        SCHED0;
        if (st)       wvm<6>();
        else if (rd1) wvm<0>();
        BARRIER; SCHED0;

        const int tmp = bs0; bs0 = bs1; bs1 = bs2; bs2 = tmp;
    }

    const int mbase = bm * 256 + wm * 64;
    const int nbase = bn * 128 + wn * 64;
#pragma unroll
    for (int mi = 0; mi < 4; ++mi) {
        const int m = mbase + mi * 16 + l16;
#pragma unroll
        for (int ni = 0; ni < 4; ++ni) {
            const int n0 = nbase + ni * 16 + quad * 4;
            const float4 bv = *(const float4*)&bias[n0];
            float4 o = { acc[mi][ni][0] + bv.x, acc[mi][ni][1] + bv.y,
                         acc[mi][ni][2] + bv.z, acc[mi][ni][3] + bv.w };
            *(float4*)&Cout[(size_t)m * N + n0] = o;
        }
    }
}

// ---------------------------------------------------------------------------
// inputs: 0 act(4,2048,1024) f32, 1 mask(unused), 2 ln_scale(1024),
//         3 ln_bias(1024), 4 w1(1024,4096), 5 b1(4096), 6 w2(4096,1024),
//         7 b2(1024). out: (4,2048,1024) f32.
// ws (bf16 bits): X[8192*1024] | W1t[4096*1024] | W2t[1024*4096] | H[8192*4096]
// ---------------------------------------------------------------------------
extern "C" void kernel_launch(void* const* d_in, const int* in_sizes, int n_in,
                              void* d_out, int out_size, void* d_ws, size_t ws_size,
                              hipStream_t stream)
{
    const float* act      = (const float*)d_in[0];
    const float* ln_scale = (const float*)d_in[2];
    const float* ln_bias  = (const float*)d_in[3];
    const float* w1       = (const float*)d_in[4];
    const float* b1       = (const float*)d_in[5];
    const float* w2       = (const float*)d_in[6];
    const float* b2       = (const float*)d_in[7];
    float* out = (float*)d_out;

    const int M = 8192, C = 1024, CI = 4096;

    u16* X   = (u16*)d_ws;                 // [M][C]
    u16* W1t = X   + (size_t)M * C;        // [CI][C]
    u16* W2t = W1t + (size_t)CI * C;       // [C][CI]
    u16* H   = W2t + (size_t)C * CI;       // [M][CI]

    prep<<<10240, 256, 0, stream>>>(w1, w2, act, ln_scale, ln_bias, W1t, W2t, X);
    // H = relu(X @ W1 + b1): 512 blocks, m201-exact 2-bar phases, A-dbuf +
    // B-triple (160KB LDS), all-counted vmcnt
    gemm1<<<(M / 256) * (CI / 256), 512, 0, stream>>>(X, W1t, b1, H);
    // out = H @ W2 + b2: 256 blocks = 1/CU, cross-tile read-ahead (R11)
    gemm2<<<(M / 256) * (C / 128), 512, 0, stream>>>(H, W2t, b2, out);
}